// Round 7
// baseline (263.076 us; speedup 1.0000x reference)
//
#include <hip/hip_runtime.h>
#include <hip/hip_bf16.h>
#include <cmath>

#define NB 4
#define NS 1024
#define ND 1024
#define NH 16
#define NDH 64
#define NKSP 32
#define SCALE 0.125f      // 1/sqrt(64)
#define LOG2E 1.44269504f
#define SCALE2 (SCALE * LOG2E)

typedef __attribute__((ext_vector_type(8))) short bf16x8;
typedef __attribute__((ext_vector_type(4))) float f32x4;
typedef unsigned long long u64;

#define AS1 __attribute__((address_space(1)))
#define AS3 __attribute__((address_space(3)))

__device__ __forceinline__ void gl_lds16(const void* g, void* l) {
    __builtin_amdgcn_global_load_lds((const AS1 void*)g, (AS3 void*)l, 16, 0, 0);
}

__device__ __forceinline__ ushort f2bf(float f) {
    union { __hip_bfloat16 h; ushort u; } cv;
    cv.h = __float2bfloat16(f);
    return cv.u;
}
__device__ __forceinline__ float bf2f(ushort u) {
    union { unsigned int i; float f; } cv;
    cv.i = ((unsigned int)u) << 16;
    return cv.f;
}
__device__ __forceinline__ float fexp2(float x) {
    return __builtin_amdgcn_exp2f(x);   // v_exp_f32 (base-2)
}

// ---------------------------------------------------------------------------
// y=0: x->bf16 (4096 blocks); y=1..4: W->bf16 (1024 blocks);
// y=5: pack pmask into bitwords (4096 blocks, one wave per u64 word).
// ---------------------------------------------------------------------------
__global__ __launch_bounds__(256)
void f2bf_multi(const float* __restrict__ x,
                const float* __restrict__ w0, const float* __restrict__ w1,
                const float* __restrict__ w2, const float* __restrict__ w3,
                const int* __restrict__ pm,
                ushort* __restrict__ xo,
                ushort* __restrict__ o0, ushort* __restrict__ o1,
                ushort* __restrict__ o2, ushort* __restrict__ o3,
                u64* __restrict__ bm)
{
    int y = blockIdx.y;
    if (y == 5) {
        int word = blockIdx.x * 4 + (threadIdx.x >> 6);
        int lane = threadIdx.x & 63;
        int row  = word >> 4, wcol = word & 15;
        int v = pm[(size_t)row * NS + wcol * 64 + lane];
        u64 b = __ballot(v != 0);
        if (lane == 0) bm[word] = b;
        return;
    }
    const float* src; ushort* dst; int nblk;
    if (y == 0)      { src = x;  dst = xo; nblk = 4096; }
    else if (y == 1) { src = w0; dst = o0; nblk = 1024; }
    else if (y == 2) { src = w1; dst = o1; nblk = 1024; }
    else if (y == 3) { src = w2; dst = o2; nblk = 1024; }
    else             { src = w3; dst = o3; nblk = 1024; }
    if (blockIdx.x >= (unsigned)nblk) return;
    int i = (blockIdx.x * 256 + threadIdx.x) * 4;
    float4 v = *(const float4*)&src[i];
    ushort4 o;
    o.x = f2bf(v.x); o.y = f2bf(v.y); o.z = f2bf(v.z); o.w = f2bf(v.w);
    *(ushort4*)&dst[i] = o;
}

// ---------------------------------------------------------------------------
// Fused QKV GEMM (direct-scatter epilogue; V also writes Vt).
// grid (24,32): blockIdx.x: [0,8)=Q [8,16)=K [16,24)=V.
// ---------------------------------------------------------------------------
__global__ __launch_bounds__(256)
void gemm_qkv(const ushort* __restrict__ xb,
              const ushort* __restrict__ Wqb, const ushort* __restrict__ Wkb,
              const ushort* __restrict__ Wvb,
              const float* __restrict__ bq, const float* __restrict__ bk,
              const float* __restrict__ bv,
              ushort* __restrict__ Qo, ushort* __restrict__ Ko,
              ushort* __restrict__ Vo, ushort* __restrict__ Vto)
{
    constexpr int K = ND;
    __shared__ __attribute__((aligned(16))) ushort As[128 * 32];
    __shared__ __attribute__((aligned(16))) ushort Bs[128 * 32];

    const int tid  = threadIdx.x;
    const int lane = tid & 63, w = tid >> 6;
    const int wm = w >> 1, wn = w & 1;
    const int which = blockIdx.x >> 3;
    const int n0 = (blockIdx.x & 7) * 128;
    const int m0 = blockIdx.y * 128;
    const int quad = lane >> 4, l16 = lane & 15;

    const ushort* W = (which == 0) ? Wqb : (which == 1) ? Wkb : Wvb;
    const float* bias = (which == 0) ? bq : (which == 1) ? bk : bv;
    ushort* Out = (which == 0) ? Qo : (which == 1) ? Ko : Vo;

    f32x4 acc[4][4] = {};

    for (int k0 = 0; k0 < K; k0 += 32) {
        __syncthreads();
#pragma unroll
        for (int u = 0; u < 2; ++u) {
            int t0 = u * 256 + w * 64;
            int t  = t0 + lane;
            int row = t >> 2, kc = (t & 3) * 8;
            gl_lds16(xb + (size_t)(m0 + row) * K + k0 + kc, &As[t0 * 8]);
            gl_lds16(W  + (size_t)(n0 + row) * K + k0 + kc, &Bs[t0 * 8]);
        }
        __syncthreads();

        bf16x8 af[4], bfr[4];
#pragma unroll
        for (int mt = 0; mt < 4; ++mt)
            af[mt] = *(const bf16x8*)&As[(wm*64 + mt*16 + l16) * 32 + quad*8];
#pragma unroll
        for (int nt = 0; nt < 4; ++nt)
            bfr[nt] = *(const bf16x8*)&Bs[(wn*64 + nt*16 + l16) * 32 + quad*8];
#pragma unroll
        for (int mt = 0; mt < 4; ++mt)
#pragma unroll
            for (int nt = 0; nt < 4; ++nt)
                acc[mt][nt] = __builtin_amdgcn_mfma_f32_16x16x32_bf16(
                    af[mt], bfr[nt], acc[mt][nt], 0, 0, 0);
    }

#pragma unroll
    for (int nt = 0; nt < 4; ++nt) {
        int n = n0 + wn*64 + nt*16 + l16;
        float bz = bias[n];
        int hh = n >> 6, dh = n & 63;
#pragma unroll
        for (int mt = 0; mt < 4; ++mt) {
#pragma unroll
            for (int rg = 0; rg < 4; ++rg) {
                int m = m0 + wm*64 + mt*16 + quad*4 + rg;
                int b = m >> 10, s = m & (NS - 1);
                ushort val = f2bf(acc[mt][nt][rg] + bz);
                Out[(((size_t)(b*NH + hh))*NS + s)*NDH + dh] = val;
                if (which == 2)
                    Vto[(((size_t)(b*NH + hh))*NDH + dh)*NS + s] = val;
            }
        }
    }
}

// ---------------------------------------------------------------------------
// Output GEMM: 64x128 tile -> 512 blocks.
// ---------------------------------------------------------------------------
__global__ __launch_bounds__(256)
void gemm_out(const ushort* __restrict__ A, const ushort* __restrict__ W,
              const float* __restrict__ bias, float* __restrict__ Cout)
{
    constexpr int K = ND;
    __shared__ __attribute__((aligned(16))) ushort As[64 * 32];
    __shared__ __attribute__((aligned(16))) ushort Bs[128 * 32];

    const int tid  = threadIdx.x;
    const int lane = tid & 63, w = tid >> 6;
    const int wm = w & 1, wn = w >> 1;
    const int m0 = blockIdx.y * 64, n0 = blockIdx.x * 128;
    const int quad = lane >> 4, l16 = lane & 15;

    f32x4 acc[2][4] = {};

    for (int k0 = 0; k0 < K; k0 += 32) {
        __syncthreads();
        {
            int t0 = w * 64;
            int t  = t0 + lane;
            int row = t >> 2, kc = (t & 3) * 8;
            gl_lds16(A + (size_t)(m0 + row) * K + k0 + kc, &As[t0 * 8]);
        }
#pragma unroll
        for (int u = 0; u < 2; ++u) {
            int t0 = u * 256 + w * 64;
            int t  = t0 + lane;
            int row = t >> 2, kc = (t & 3) * 8;
            gl_lds16(W + (size_t)(n0 + row) * K + k0 + kc, &Bs[t0 * 8]);
        }
        __syncthreads();

        bf16x8 af[2], bfr[4];
#pragma unroll
        for (int mt = 0; mt < 2; ++mt)
            af[mt] = *(const bf16x8*)&As[(wm*32 + mt*16 + l16) * 32 + quad*8];
#pragma unroll
        for (int nt = 0; nt < 4; ++nt)
            bfr[nt] = *(const bf16x8*)&Bs[(wn*64 + nt*16 + l16) * 32 + quad*8];
#pragma unroll
        for (int mt = 0; mt < 2; ++mt)
#pragma unroll
            for (int nt = 0; nt < 4; ++nt)
                acc[mt][nt] = __builtin_amdgcn_mfma_f32_16x16x32_bf16(
                    af[mt], bfr[nt], acc[mt][nt], 0, 0, 0);
    }

#pragma unroll
    for (int nt = 0; nt < 4; ++nt) {
        int n = n0 + wn*64 + nt*16 + l16;
        float bz = bias[n];
#pragma unroll
        for (int mt = 0; mt < 2; ++mt) {
#pragma unroll
            for (int rg = 0; rg < 4; ++rg) {
                int m = m0 + wm*32 + mt*16 + quad*4 + rg;
                Cout[(size_t)m * ND + n] = acc[mt][nt][rg] + bz;
            }
        }
    }
}

// ---------------------------------------------------------------------------
// MFMA flash attention, round 7: dense-first remap + 4 blocks/CU.
// Post-mortem r6 (71.7us): compute per dense block is ~2us but blocks take
// ~30us; with 59KB LDS only 2 blocks/CU resident, and the dense/sparse
// arrival mix makes each CU run its ~2 dense blocks mostly SEQUENTIALLY
// (sparse co-residents finish in us). Critical path ~ 2 x T_dense_solo at
// 1-2 waves/SIMD. Fix = co-residency, two parts:
//  (1) Dense-first remap (device-side): every block classifies the 4
//      batches from u_prev (uniform, deterministic), and ids [0,nd*256)
//      take dense items, rest sparse. All dense blocks co-resident from
//      t=0. XCD locality kept: head = hi*8 + (id&7).
//  (2) LDS 58->34.8KB => 4 blocks/CU (16 waves/CU, 4/SIMD): single-buffer
//      K stage (stage latency covered by cross-block TLP, barriers don't
//      couple different blocks), mask words gathered from L2-resident bm
//      into regs (MW stage dropped), combine buffer aliased onto dead
//      KK+Ps. K-split waves kept (r6's +13%): wk parity, additive o/l.
// LDS = KK 16384 + Ps 18432 = 34816 B. __launch_bounds__(256,4): VGPR
// cap 128 (r6 used 96 — headroom, no r2-style spill).
// ---------------------------------------------------------------------------

// Stage kt-pair (PT, PT+1) K-tiles into KK (1024 16B chunks, 4 waves x 4).
// Source chunk-swizzled sub^=(row&7) (rule #21: swizzle source + read).
#define STAGE(PT)                                                             \
    _Pragma("unroll")                                                         \
    for (int u = 0; u < 4; ++u) {                                             \
        int cb = w * 256 + u * 64;                                            \
        int c  = cb + lane;                                                   \
        int wk2 = c >> 9, c2 = c & 511;                                       \
        int row = c2 >> 3, sub = c2 & 7;                                      \
        const ushort* src = Kh + (((size_t)(((PT) + wk2)*64 + row)) << 6)     \
                               + ((sub ^ (row & 7)) << 3);                    \
        gl_lds16(src, KK + (size_t)cb * 8);                                   \
    }

// K fragments from LDS (swizzled chunk), V fragments direct from global.
#define LOADKV(KF, VF, KT)                                                    \
    _Pragma("unroll")                                                         \
    for (int nt = 0; nt < 4; ++nt)                                            \
        _Pragma("unroll")                                                     \
        for (int kk = 0; kk < 2; ++kk) {                                      \
            int rowk = nt*16 + l16;                                           \
            int ck = (kk*4 + quad) ^ (l16 & 7);                               \
            KF[nt][kk] = *(const bf16x8*)&KK[wk*4096 + rowk*64 + ck*8];       \
            VF[nt][kk] = *(const bf16x8*)                                     \
                &Vth[(size_t)(nt*16 + l16) * NS + (KT)*64 + kk*32 + quad*8];  \
        }

// One K-tile step: both qh halves of this wave's 32 rows. M0/M1 = raw
// bm words for qh=0/1 (prefetched before the QK cluster).
#define STEP(KF, VF, M0, M1)                                                  \
    _Pragma("unroll")                                                         \
    for (int qh = 0; qh < 2; ++qh) {                                          \
        const int qrow = wq*32 + qh*16 + l16;                                 \
        u64 wqm = ((qh == 0) ? (M0) : (M1)) >> (quad * 4);                    \
        f32x4 s_acc[4] = {};                                                  \
        __builtin_amdgcn_s_setprio(1);                                        \
        _Pragma("unroll")                                                     \
        for (int nt = 0; nt < 4; ++nt)                                        \
            _Pragma("unroll")                                                 \
            for (int kk = 0; kk < 2; ++kk)                                    \
                s_acc[nt] = __builtin_amdgcn_mfma_f32_16x16x32_bf16(          \
                    KF[nt][kk], qf[qh][kk], s_acc[nt], 0, 0, 0);              \
        __builtin_amdgcn_s_setprio(0);                                        \
        _Pragma("unroll")                                                     \
        for (int nt = 0; nt < 4; ++nt) {                                      \
            ushort4 pk;                                                       \
            float p0 = fexp2(fmaf(s_acc[nt][0], SCALE2,                       \
                 ((wqm >> (nt*16 + 0)) & 1ULL) ? 0.f : nlam2));               \
            float p1 = fexp2(fmaf(s_acc[nt][1], SCALE2,                       \
                 ((wqm >> (nt*16 + 1)) & 1ULL) ? 0.f : nlam2));               \
            float p2 = fexp2(fmaf(s_acc[nt][2], SCALE2,                       \
                 ((wqm >> (nt*16 + 2)) & 1ULL) ? 0.f : nlam2));               \
            float p3 = fexp2(fmaf(s_acc[nt][3], SCALE2,                       \
                 ((wqm >> (nt*16 + 3)) & 1ULL) ? 0.f : nlam2));               \
            pk.x = f2bf(p0); pk.y = f2bf(p1);                                 \
            pk.z = f2bf(p2); pk.w = f2bf(p3);                                 \
            *(ushort4*)&Ps[wk*4608 + qrow*72 + nt*16 + quad*4] = pk;          \
        }                                                                     \
        bf16x8 pf[2];                                                         \
        _Pragma("unroll")                                                     \
        for (int kk = 0; kk < 2; ++kk)                                        \
            pf[kk] = *(const bf16x8*)&Ps[wk*4608 + qrow*72 + kk*32 + quad*8]; \
        __builtin_amdgcn_s_setprio(1);                                        \
        _Pragma("unroll")                                                     \
        for (int kk = 0; kk < 2; ++kk) {                                      \
            l_acc[qh] = __builtin_amdgcn_mfma_f32_16x16x32_bf16(              \
                pf[kk], ones.v, l_acc[qh], 0, 0, 0);                          \
            _Pragma("unroll")                                                 \
            for (int nt = 0; nt < 4; ++nt)                                    \
                o_acc[qh][nt] = __builtin_amdgcn_mfma_f32_16x16x32_bf16(      \
                    pf[kk], VF[nt][kk], o_acc[qh][nt], 0, 0, 0);              \
        }                                                                     \
        __builtin_amdgcn_s_setprio(0);                                        \
    }

__global__ __launch_bounds__(256, 4)
void attn_kernel(const ushort* __restrict__ Qb, const ushort* __restrict__ Kb,
                 const ushort* __restrict__ Vb, const ushort* __restrict__ Vt,
                 const u64* __restrict__ bm,
                 const int* __restrict__ pidx, const int* __restrict__ pimask,
                 const float* __restrict__ u_prev, ushort* __restrict__ OA)
{
    // union region: KK [0, 8192) ushorts, Ps [8192, 17408) ushorts;
    // POUT (combine) aliases [0, 5120) floats after the K-loop.
    __shared__ __attribute__((aligned(16))) ushort SM[17408];
    ushort* KK = SM;
    ushort* Ps = SM + 8192;

    const int tid  = threadIdx.x;
    const int lane = tid & 63, w = tid >> 6;      // 4 waves
    const int quad = lane >> 4, l16 = lane & 15;
    const int wq = w & 1, wk = w >> 1;            // row-half / kt-parity

    // ---- classify batches (uniform across ALL blocks: same u_prev math) --
    float lams[4];
#pragma unroll
    for (int i = 0; i < 4; ++i) lams[i] = 10.0f * __expf(-5.0f * u_prev[i]);
    int dl[4], sl[4], nd = 0, ns = 0;
#pragma unroll
    for (int i = 0; i < 4; ++i) if (lams[i] <  1.0f) dl[nd++] = i;
#pragma unroll
    for (int i = 0; i < 4; ++i) if (lams[i] >= 1.0f) sl[ns++] = i;

    // ---- dense-first work remap (ids [0, nd*256) = dense items) ----------
    const int id = blockIdx.x;                    // 0..1023
    bool sparse; int b, h, qtile;
    if (id < nd * 256) {
        sparse = false;
        int xcd = id & 7, j = id >> 3;            // j in [0, nd*32)
        int nh2 = 2 * nd;
        int hi = j % nh2, qt = j / nh2;           // head-slot on xcd / qtile
        int gh = hi * 8 + xcd;                    // dense-head idx [0,16*nd)
        b = dl[gh >> 4]; h = gh & 15; qtile = qt;
    } else {
        sparse = true;
        int d = id - nd * 256;
        int xcd = d & 7, j = d >> 3;
        int nh2 = 2 * ns;
        int hi = j % nh2, qt = j / nh2;
        int gh = hi * 8 + xcd;
        b = sl[gh >> 4]; h = gh & 15; qtile = qt;
    }
    const int s0 = qtile * 64;
    const float lam = lams[b];

    const size_t bh = (size_t)b * NH + h;
    const ushort* Qh  = Qb + bh * NS * NDH;
    const ushort* Kh  = Kb + bh * NS * NDH;
    const ushort* Vh  = Vb + bh * NS * NDH;
    const ushort* Vth = Vt + bh * NDH * NS;

    if (!sparse) {
        const float nlam2 = -lam * LOG2E;   // base-2 bias

        // Q fragments (B-operand = Q^T) for this wave's 32 rows
        bf16x8 qf[2][2];
#pragma unroll
        for (int qh = 0; qh < 2; ++qh)
#pragma unroll
            for (int kk = 0; kk < 2; ++kk)
                qf[qh][kk] = *(const bf16x8*)
                    &Qh[(size_t)(s0 + wq*32 + qh*16 + l16) * NDH + kk*32 + quad*8];

        union { bf16x8 v; ushort s[8]; } ones;
#pragma unroll
        for (int i = 0; i < 8; ++i) ones.s[i] = 0x3F80;  // bf16 1.0

        f32x4 o_acc[2][4] = {};
        f32x4 l_acc[2] = {};

        for (int t = 0; t < 8; ++t) {
            if (t) __syncthreads();               // prior reads of KK done
            STAGE(2 * t);
            const int kt = 2 * t + wk;            // this wave's kt parity
            // mask words straight from L2-resident bm (prefetched here,
            // consumed after the QK cluster — latency hidden)
            u64 m0 = bm[(size_t)(s0 + wq*32 +  0 + l16) * 16 + kt];
            u64 m1 = bm[(size_t)(s0 + wq*32 + 16 + l16) * 16 + kt];
            __syncthreads();                      // stage visible
            bf16x8 kf[4][2], vf[4][2];
            LOADKV(kf, vf, kt);
            STEP(kf, vf, m0, m1);
        }
        __syncthreads();                          // KK/Ps dead -> POUT

        // ----- combine wk partials (o,l additive: no max normalization) ----
        float* POUT = (float*)SM;                 // 5120 floats = 20.5 KB
        if (wk == 1) {
#pragma unroll
            for (int qh = 0; qh < 2; ++qh) {
#pragma unroll
                for (int nt = 0; nt < 4; ++nt)
#pragma unroll
                    for (int rg = 0; rg < 4; ++rg)
                        POUT[(wq*40 + qh*16 + nt*4 + rg)*64 + lane] =
                            o_acc[qh][nt][rg];
#pragma unroll
                for (int rg = 0; rg < 4; ++rg)
                    POUT[(wq*40 + 32 + qh*4 + rg)*64 + lane] = l_acc[qh][rg];
            }
        }
        __syncthreads();
        if (wk == 0) {
#pragma unroll
            for (int qh = 0; qh < 2; ++qh) {
#pragma unroll
                for (int nt = 0; nt < 4; ++nt)
#pragma unroll
                    for (int rg = 0; rg < 4; ++rg)
                        o_acc[qh][nt][rg] +=
                            POUT[(wq*40 + qh*16 + nt*4 + rg)*64 + lane];
#pragma unroll
                for (int rg = 0; rg < 4; ++rg)
                    l_acc[qh][rg] += POUT[(wq*40 + 32 + qh*4 + rg)*64 + lane];
            }
            // epilogue (row=query quad*4+rg, col=dh nt*16+l16)
#pragma unroll
            for (int qh = 0; qh < 2; ++qh) {
                float inv[4];
#pragma unroll
                for (int rg = 0; rg < 4; ++rg) inv[rg] = 1.f / l_acc[qh][rg];
#pragma unroll
                for (int nt = 0; nt < 4; ++nt)
#pragma unroll
                    for (int rg = 0; rg < 4; ++rg) {
                        int m = wq*32 + qh*16 + quad*4 + rg;
                        OA[((size_t)b*NS + s0 + m)*ND + h*NDH + nt*16 + l16] =
                            f2bf(o_acc[qh][nt][rg] * inv[rg]);
                    }
            }
        }
    } else {
        // ---------------- sparse path (fp32 scalar, bf16 inputs) ----------
        const int r2  = lane & 15;
        const int cg  = lane >> 4;
        {
            const int row = w*16 + r2;            // 0..63

            float qreg[64];
            {
                const ushort* qp = Qh + (size_t)(s0 + row) * NDH;
#pragma unroll
                for (int c = 0; c < 8; ++c) {
                    union { bf16x8 v; ushort s[8]; } qv;
                    qv.v = *(const bf16x8*)(qp + c*8);
#pragma unroll
                    for (int j = 0; j < 8; ++j) qreg[c*8 + j] = bf2f(qv.s[j]);
                }
            }

            // scores: unconditional gather + select (no divergent branch)
            float sc[8];
#pragma unroll
            for (int jj = 0; jj < 8; ++jj) {
                int j  = cg*8 + jj;
                int mv = pimask[(size_t)(s0+row)*NKSP + j];
                int kv = pidx[(size_t)(s0+row)*NKSP + j];
                const ushort* krow = &Kh[(size_t)kv * NDH];
                float acc = 0.f;
#pragma unroll
                for (int c = 0; c < 8; ++c) {
                    union { bf16x8 v; ushort s[8]; } kk;
                    kk.v = *(const bf16x8*)(krow + c*8);
#pragma unroll
                    for (int jb = 0; jb < 8; ++jb)
                        acc = fmaf(qreg[c*8 + jb], bf2f(kk.s[jb]), acc);
                }
                sc[jj] = mv ? acc * SCALE : -INFINITY;
            }
            float mt = sc[0];
#pragma unroll
            for (int jj = 1; jj < 8; ++jj) mt = fmaxf(mt, sc[jj]);
            mt = fmaxf(mt, __shfl_xor(mt, 16));
            mt = fmaxf(mt, __shfl_xor(mt, 32));

            float psum = 0.f;
#pragma unroll
            for (int jj = 0; jj < 8; ++jj) {
                float p = __expf(sc[jj] - mt);
                psum += p;
                Ps[row * 72 + cg*8 + jj] = f2bf(p);
            }
            psum += __shfl_xor(psum, 16);
            psum += __shfl_xor(psum, 32);

            float o[16];
#pragma unroll
            for (int i = 0; i < 16; ++i) o[i] = 0.f;

            // PV: p=0 contributes 0 -> no branch; unroll for load pipelining
#pragma unroll 4
            for (int j = 0; j < 32; ++j) {
                float p = bf2f(Ps[row * 72 + j]);
                int kv = pidx[(size_t)(s0+row)*NKSP + j];
                const ushort* vrow = &Vh[(size_t)kv * NDH + cg*16];
#pragma unroll
                for (int c = 0; c < 2; ++c) {
                    union { bf16x8 v; ushort s[8]; } vv;
                    vv.v = *(const bf16x8*)(vrow + c*8);
#pragma unroll
                    for (int jb = 0; jb < 8; ++jb)
                        o[c*8 + jb] = fmaf(p, bf2f(vv.s[jb]), o[c*8 + jb]);
                }
            }

            float inv = 1.f / psum;
            ushort* op = OA + ((size_t)b*NS + s0 + row)*ND + h*NDH + cg*16;
#pragma unroll
            for (int i4 = 0; i4 < 4; ++i4) {
                ushort4 v;
                v.x = f2bf(o[i4*4+0]*inv); v.y = f2bf(o[i4*4+1]*inv);
                v.z = f2bf(o[i4*4+2]*inv); v.w = f2bf(o[i4*4+3]*inv);
                *(ushort4*)(op + i4*4) = v;
            }
        }
    }
}

// ---------------------------------------------------------------------------
extern "C" void kernel_launch(void* const* d_in, const int* in_sizes, int n_in,
                              void* d_out, int out_size, void* d_ws, size_t ws_size,
                              hipStream_t stream)
{
    const float* x      = (const float*)d_in[0];
    const int*   pmask  = (const int*)  d_in[1];
    const int*   pidx   = (const int*)  d_in[2];
    const int*   pimask = (const int*)  d_in[3];
    const float* u_prev = (const float*)d_in[4];
    const float* Wq     = (const float*)d_in[5];
    const float* bq     = (const float*)d_in[6];
    const float* Wk     = (const float*)d_in[7];
    const float* bk     = (const float*)d_in[8];
    const float* Wv     = (const float*)d_in[9];
    const float* bv     = (const float*)d_in[10];
    const float* Wo     = (const float*)d_in[11];
    const float* bo     = (const float*)d_in[12];
    float* out = (float*)d_out;

    const size_t QSZ = (size_t)NB * NH * NS * NDH;   // 4,194,304 elements
    const size_t WSZ = (size_t)ND * ND;              // 1,048,576 elements
    ushort* xb  = (ushort*)d_ws;        // bf16 x              (8 MB)
    ushort* Qw  = xb  + QSZ;            // bf16 Q (b,h,s,dh)   (8 MB)
    ushort* Kw  = Qw  + QSZ;            // bf16 K              (8 MB)
    ushort* Vw  = Kw  + QSZ;            // bf16 V              (8 MB)
    ushort* Vtw = Vw  + QSZ;            // bf16 V^T (b,h,dh,s) (8 MB)
    ushort* Awb = Vtw + QSZ;            // bf16 attn out       (8 MB)
    ushort* Wqb = Awb + QSZ;            // bf16 weights (2 MB each)
    ushort* Wkb = Wqb + WSZ;
    ushort* Wvb = Wkb + WSZ;
    ushort* Wob = Wvb + WSZ;
    u64*    bmw = (u64*)(Wob + WSZ);    // packed mask (128 KB)

    f2bf_multi<<<dim3(4096, 6), 256, 0, stream>>>(
        x, Wq, Wk, Wv, Wo, pmask, xb, Wqb, Wkb, Wvb, Wob, bmw);

    gemm_qkv<<<dim3(24, 32), 256, 0, stream>>>(
        xb, Wqb, Wkb, Wvb, bq, bk, bv, Qw, Kw, Vw, Vtw);

    attn_kernel<<<1024, 256, 0, stream>>>(
        Qw, Kw, Vw, Vtw, bmw, pidx, pimask, u_prev, Awb);

    gemm_out<<<dim3(ND/128, (NB*NS)/64), 256, 0, stream>>>(Awb, Wob, bo, out);
}

// Round 8
// 227.645 us; speedup vs baseline: 1.1556x; 1.1556x over previous
//
#include <hip/hip_runtime.h>
#include <hip/hip_bf16.h>
#include <cmath>

#define NB 4
#define NS 1024
#define ND 1024
#define NH 16
#define NDH 64
#define NKSP 32
#define SCALE 0.125f      // 1/sqrt(64)
#define LOG2E 1.44269504f
#define SCALE2 (SCALE * LOG2E)

typedef __attribute__((ext_vector_type(8))) short bf16x8;
typedef __attribute__((ext_vector_type(4))) float f32x4;
typedef unsigned long long u64;

#define AS1 __attribute__((address_space(1)))
#define AS3 __attribute__((address_space(3)))

__device__ __forceinline__ void gl_lds16(const void* g, void* l) {
    __builtin_amdgcn_global_load_lds((const AS1 void*)g, (AS3 void*)l, 16, 0, 0);
}

__device__ __forceinline__ ushort f2bf(float f) {
    union { __hip_bfloat16 h; ushort u; } cv;
    cv.h = __float2bfloat16(f);
    return cv.u;
}
__device__ __forceinline__ float bf2f(ushort u) {
    union { unsigned int i; float f; } cv;
    cv.i = ((unsigned int)u) << 16;
    return cv.f;
}
__device__ __forceinline__ float fexp2(float x) {
    return __builtin_amdgcn_exp2f(x);   // v_exp_f32 (base-2)
}

// ---------------------------------------------------------------------------
// y=0: x->bf16 (4096 blocks); y=1..4: W->bf16 (1024 blocks);
// y=5: pack pmask into bitwords (4096 blocks, one wave per u64 word).
// ---------------------------------------------------------------------------
__global__ __launch_bounds__(256)
void f2bf_multi(const float* __restrict__ x,
                const float* __restrict__ w0, const float* __restrict__ w1,
                const float* __restrict__ w2, const float* __restrict__ w3,
                const int* __restrict__ pm,
                ushort* __restrict__ xo,
                ushort* __restrict__ o0, ushort* __restrict__ o1,
                ushort* __restrict__ o2, ushort* __restrict__ o3,
                u64* __restrict__ bm)
{
    int y = blockIdx.y;
    if (y == 5) {
        int word = blockIdx.x * 4 + (threadIdx.x >> 6);
        int lane = threadIdx.x & 63;
        int row  = word >> 4, wcol = word & 15;
        int v = pm[(size_t)row * NS + wcol * 64 + lane];
        u64 b = __ballot(v != 0);
        if (lane == 0) bm[word] = b;
        return;
    }
    const float* src; ushort* dst; int nblk;
    if (y == 0)      { src = x;  dst = xo; nblk = 4096; }
    else if (y == 1) { src = w0; dst = o0; nblk = 1024; }
    else if (y == 2) { src = w1; dst = o1; nblk = 1024; }
    else if (y == 3) { src = w2; dst = o2; nblk = 1024; }
    else             { src = w3; dst = o3; nblk = 1024; }
    if (blockIdx.x >= (unsigned)nblk) return;
    int i = (blockIdx.x * 256 + threadIdx.x) * 4;
    float4 v = *(const float4*)&src[i];
    ushort4 o;
    o.x = f2bf(v.x); o.y = f2bf(v.y); o.z = f2bf(v.z); o.w = f2bf(v.w);
    *(ushort4*)&dst[i] = o;
}

// ---------------------------------------------------------------------------
// Fused QKV GEMM (direct-scatter epilogue; V also writes Vt).
// grid (24,32): blockIdx.x: [0,8)=Q [8,16)=K [16,24)=V.
// ---------------------------------------------------------------------------
__global__ __launch_bounds__(256)
void gemm_qkv(const ushort* __restrict__ xb,
              const ushort* __restrict__ Wqb, const ushort* __restrict__ Wkb,
              const ushort* __restrict__ Wvb,
              const float* __restrict__ bq, const float* __restrict__ bk,
              const float* __restrict__ bv,
              ushort* __restrict__ Qo, ushort* __restrict__ Ko,
              ushort* __restrict__ Vo, ushort* __restrict__ Vto)
{
    constexpr int K = ND;
    __shared__ __attribute__((aligned(16))) ushort As[128 * 32];
    __shared__ __attribute__((aligned(16))) ushort Bs[128 * 32];

    const int tid  = threadIdx.x;
    const int lane = tid & 63, w = tid >> 6;
    const int wm = w >> 1, wn = w & 1;
    const int which = blockIdx.x >> 3;
    const int n0 = (blockIdx.x & 7) * 128;
    const int m0 = blockIdx.y * 128;
    const int quad = lane >> 4, l16 = lane & 15;

    const ushort* W = (which == 0) ? Wqb : (which == 1) ? Wkb : Wvb;
    const float* bias = (which == 0) ? bq : (which == 1) ? bk : bv;
    ushort* Out = (which == 0) ? Qo : (which == 1) ? Ko : Vo;

    f32x4 acc[4][4] = {};

    for (int k0 = 0; k0 < K; k0 += 32) {
        __syncthreads();
#pragma unroll
        for (int u = 0; u < 2; ++u) {
            int t0 = u * 256 + w * 64;
            int t  = t0 + lane;
            int row = t >> 2, kc = (t & 3) * 8;
            gl_lds16(xb + (size_t)(m0 + row) * K + k0 + kc, &As[t0 * 8]);
            gl_lds16(W  + (size_t)(n0 + row) * K + k0 + kc, &Bs[t0 * 8]);
        }
        __syncthreads();

        bf16x8 af[4], bfr[4];
#pragma unroll
        for (int mt = 0; mt < 4; ++mt)
            af[mt] = *(const bf16x8*)&As[(wm*64 + mt*16 + l16) * 32 + quad*8];
#pragma unroll
        for (int nt = 0; nt < 4; ++nt)
            bfr[nt] = *(const bf16x8*)&Bs[(wn*64 + nt*16 + l16) * 32 + quad*8];
#pragma unroll
        for (int mt = 0; mt < 4; ++mt)
#pragma unroll
            for (int nt = 0; nt < 4; ++nt)
                acc[mt][nt] = __builtin_amdgcn_mfma_f32_16x16x32_bf16(
                    af[mt], bfr[nt], acc[mt][nt], 0, 0, 0);
    }

#pragma unroll
    for (int nt = 0; nt < 4; ++nt) {
        int n = n0 + wn*64 + nt*16 + l16;
        float bz = bias[n];
        int hh = n >> 6, dh = n & 63;
#pragma unroll
        for (int mt = 0; mt < 4; ++mt) {
#pragma unroll
            for (int rg = 0; rg < 4; ++rg) {
                int m = m0 + wm*64 + mt*16 + quad*4 + rg;
                int b = m >> 10, s = m & (NS - 1);
                ushort val = f2bf(acc[mt][nt][rg] + bz);
                Out[(((size_t)(b*NH + hh))*NS + s)*NDH + dh] = val;
                if (which == 2)
                    Vto[(((size_t)(b*NH + hh))*NDH + dh)*NS + s] = val;
            }
        }
    }
}

// ---------------------------------------------------------------------------
// Output GEMM: 64x128 tile -> 512 blocks.
// ---------------------------------------------------------------------------
__global__ __launch_bounds__(256)
void gemm_out(const ushort* __restrict__ A, const ushort* __restrict__ W,
              const float* __restrict__ bias, float* __restrict__ Cout)
{
    constexpr int K = ND;
    __shared__ __attribute__((aligned(16))) ushort As[64 * 32];
    __shared__ __attribute__((aligned(16))) ushort Bs[128 * 32];

    const int tid  = threadIdx.x;
    const int lane = tid & 63, w = tid >> 6;
    const int wm = w & 1, wn = w >> 1;
    const int m0 = blockIdx.y * 64, n0 = blockIdx.x * 128;
    const int quad = lane >> 4, l16 = lane & 15;

    f32x4 acc[2][4] = {};

    for (int k0 = 0; k0 < K; k0 += 32) {
        __syncthreads();
        {
            int t0 = w * 64;
            int t  = t0 + lane;
            int row = t >> 2, kc = (t & 3) * 8;
            gl_lds16(A + (size_t)(m0 + row) * K + k0 + kc, &As[t0 * 8]);
        }
#pragma unroll
        for (int u = 0; u < 2; ++u) {
            int t0 = u * 256 + w * 64;
            int t  = t0 + lane;
            int row = t >> 2, kc = (t & 3) * 8;
            gl_lds16(W + (size_t)(n0 + row) * K + k0 + kc, &Bs[t0 * 8]);
        }
        __syncthreads();

        bf16x8 af[2], bfr[4];
#pragma unroll
        for (int mt = 0; mt < 2; ++mt)
            af[mt] = *(const bf16x8*)&As[(wm*32 + mt*16 + l16) * 32 + quad*8];
#pragma unroll
        for (int nt = 0; nt < 4; ++nt)
            bfr[nt] = *(const bf16x8*)&Bs[(wn*64 + nt*16 + l16) * 32 + quad*8];
#pragma unroll
        for (int mt = 0; mt < 2; ++mt)
#pragma unroll
            for (int nt = 0; nt < 4; ++nt)
                acc[mt][nt] = __builtin_amdgcn_mfma_f32_16x16x32_bf16(
                    af[mt], bfr[nt], acc[mt][nt], 0, 0, 0);
    }

#pragma unroll
    for (int nt = 0; nt < 4; ++nt) {
        int n = n0 + wn*64 + nt*16 + l16;
        float bz = bias[n];
#pragma unroll
        for (int mt = 0; mt < 2; ++mt) {
#pragma unroll
            for (int rg = 0; rg < 4; ++rg) {
                int m = m0 + wm*32 + mt*16 + quad*4 + rg;
                Cout[(size_t)m * ND + n] = acc[mt][nt][rg] + bz;
            }
        }
    }
}

// ---------------------------------------------------------------------------
// MFMA flash attention, round 8 = round 7 minus the register cap.
// Post-mortem r7: __launch_bounds__(256,4) forced VGPR to 64 -> full spill
// (WRITE_SIZE 8->82MB, FETCH 19->40MB) — exactly the r2 failure mode. The
// STRUCTURE worked (occupancy 17->40%): dense-first remap + 34.8KB LDS put
// 4 blocks/CU resident. Fix: __launch_bounds__(256,2) — r6 compiled this
// same body at 96 VGPR under that bound, and 96 <= 128 means the HW reaches
// 4 waves/SIMD naturally, no cap required. (Rule, twice measured: never
// min-waves > 2 here.)
// Structure (from r7):
//  (1) Dense-first remap (device-side): blocks classify the 4 batches from
//      u_prev (uniform), ids [0,nd*256) take dense items -> all dense
//      blocks co-resident from t=0. XCD locality: head = hi*8 + (id&7).
//  (2) LDS 34.8KB (KK 16K single-buffer + Ps 18K, POUT aliased) => 4
//      blocks/CU; K-stage latency covered by cross-block TLP; mask words
//      per kt gathered straight from L2-resident bm into regs.
//  (3) K-split waves (r6's +13%): wk = kt parity, additive o/l partials,
//      LDS combine at end. V direct-gather (perf-neutral, r0-r4).
// ---------------------------------------------------------------------------

// Stage kt-pair (PT, PT+1) K-tiles into KK (1024 16B chunks, 4 waves x 4).
// Source chunk-swizzled sub^=(row&7) (rule #21: swizzle source + read).
#define STAGE(PT)                                                             \
    _Pragma("unroll")                                                         \
    for (int u = 0; u < 4; ++u) {                                             \
        int cb = w * 256 + u * 64;                                            \
        int c  = cb + lane;                                                   \
        int wk2 = c >> 9, c2 = c & 511;                                       \
        int row = c2 >> 3, sub = c2 & 7;                                      \
        const ushort* src = Kh + (((size_t)(((PT) + wk2)*64 + row)) << 6)     \
                               + ((sub ^ (row & 7)) << 3);                    \
        gl_lds16(src, KK + (size_t)cb * 8);                                   \
    }

// K fragments from LDS (swizzled chunk), V fragments direct from global.
#define LOADKV(KF, VF, KT)                                                    \
    _Pragma("unroll")                                                         \
    for (int nt = 0; nt < 4; ++nt)                                            \
        _Pragma("unroll")                                                     \
        for (int kk = 0; kk < 2; ++kk) {                                      \
            int rowk = nt*16 + l16;                                           \
            int ck = (kk*4 + quad) ^ (l16 & 7);                               \
            KF[nt][kk] = *(const bf16x8*)&KK[wk*4096 + rowk*64 + ck*8];       \
            VF[nt][kk] = *(const bf16x8*)                                     \
                &Vth[(size_t)(nt*16 + l16) * NS + (KT)*64 + kk*32 + quad*8];  \
        }

// One K-tile step: both qh halves of this wave's 32 rows. M0/M1 = raw
// bm words for qh=0/1 (prefetched before the QK cluster).
#define STEP(KF, VF, M0, M1)                                                  \
    _Pragma("unroll")                                                         \
    for (int qh = 0; qh < 2; ++qh) {                                          \
        const int qrow = wq*32 + qh*16 + l16;                                 \
        u64 wqm = ((qh == 0) ? (M0) : (M1)) >> (quad * 4);                    \
        f32x4 s_acc[4] = {};                                                  \
        __builtin_amdgcn_s_setprio(1);                                        \
        _Pragma("unroll")                                                     \
        for (int nt = 0; nt < 4; ++nt)                                        \
            _Pragma("unroll")                                                 \
            for (int kk = 0; kk < 2; ++kk)                                    \
                s_acc[nt] = __builtin_amdgcn_mfma_f32_16x16x32_bf16(          \
                    KF[nt][kk], qf[qh][kk], s_acc[nt], 0, 0, 0);              \
        __builtin_amdgcn_s_setprio(0);                                        \
        _Pragma("unroll")                                                     \
        for (int nt = 0; nt < 4; ++nt) {                                      \
            ushort4 pk;                                                       \
            float p0 = fexp2(fmaf(s_acc[nt][0], SCALE2,                       \
                 ((wqm >> (nt*16 + 0)) & 1ULL) ? 0.f : nlam2));               \
            float p1 = fexp2(fmaf(s_acc[nt][1], SCALE2,                       \
                 ((wqm >> (nt*16 + 1)) & 1ULL) ? 0.f : nlam2));               \
            float p2 = fexp2(fmaf(s_acc[nt][2], SCALE2,                       \
                 ((wqm >> (nt*16 + 2)) & 1ULL) ? 0.f : nlam2));               \
            float p3 = fexp2(fmaf(s_acc[nt][3], SCALE2,                       \
                 ((wqm >> (nt*16 + 3)) & 1ULL) ? 0.f : nlam2));               \
            pk.x = f2bf(p0); pk.y = f2bf(p1);                                 \
            pk.z = f2bf(p2); pk.w = f2bf(p3);                                 \
            *(ushort4*)&Ps[wk*4608 + qrow*72 + nt*16 + quad*4] = pk;          \
        }                                                                     \
        bf16x8 pf[2];                                                         \
        _Pragma("unroll")                                                     \
        for (int kk = 0; kk < 2; ++kk)                                        \
            pf[kk] = *(const bf16x8*)&Ps[wk*4608 + qrow*72 + kk*32 + quad*8]; \
        __builtin_amdgcn_s_setprio(1);                                        \
        _Pragma("unroll")                                                     \
        for (int kk = 0; kk < 2; ++kk) {                                      \
            l_acc[qh] = __builtin_amdgcn_mfma_f32_16x16x32_bf16(              \
                pf[kk], ones.v, l_acc[qh], 0, 0, 0);                          \
            _Pragma("unroll")                                                 \
            for (int nt = 0; nt < 4; ++nt)                                    \
                o_acc[qh][nt] = __builtin_amdgcn_mfma_f32_16x16x32_bf16(      \
                    pf[kk], VF[nt][kk], o_acc[qh][nt], 0, 0, 0);              \
        }                                                                     \
        __builtin_amdgcn_s_setprio(0);                                        \
    }

__global__ __launch_bounds__(256, 2)
void attn_kernel(const ushort* __restrict__ Qb, const ushort* __restrict__ Kb,
                 const ushort* __restrict__ Vb, const ushort* __restrict__ Vt,
                 const u64* __restrict__ bm,
                 const int* __restrict__ pidx, const int* __restrict__ pimask,
                 const float* __restrict__ u_prev, ushort* __restrict__ OA)
{
    // union region: KK [0, 8192) ushorts, Ps [8192, 17408) ushorts;
    // POUT (combine) aliases [0, 5120) floats after the K-loop.
    __shared__ __attribute__((aligned(16))) ushort SM[17408];
    ushort* KK = SM;
    ushort* Ps = SM + 8192;

    const int tid  = threadIdx.x;
    const int lane = tid & 63, w = tid >> 6;      // 4 waves
    const int quad = lane >> 4, l16 = lane & 15;
    const int wq = w & 1, wk = w >> 1;            // row-half / kt-parity

    // ---- classify batches (uniform across ALL blocks: same u_prev math) --
    float lams[4];
#pragma unroll
    for (int i = 0; i < 4; ++i) lams[i] = 10.0f * __expf(-5.0f * u_prev[i]);
    int dl[4], sl[4], nd = 0, ns = 0;
#pragma unroll
    for (int i = 0; i < 4; ++i) if (lams[i] <  1.0f) dl[nd++] = i;
#pragma unroll
    for (int i = 0; i < 4; ++i) if (lams[i] >= 1.0f) sl[ns++] = i;

    // ---- dense-first work remap (ids [0, nd*256) = dense items) ----------
    const int id = blockIdx.x;                    // 0..1023
    bool sparse; int b, h, qtile;
    if (id < nd * 256) {
        sparse = false;
        int xcd = id & 7, j = id >> 3;            // j in [0, nd*32)
        int nh2 = 2 * nd;
        int hi = j % nh2, qt = j / nh2;           // head-slot on xcd / qtile
        int gh = hi * 8 + xcd;                    // dense-head idx [0,16*nd)
        b = dl[gh >> 4]; h = gh & 15; qtile = qt;
    } else {
        sparse = true;
        int d = id - nd * 256;
        int xcd = d & 7, j = d >> 3;
        int nh2 = 2 * ns;
        int hi = j % nh2, qt = j / nh2;
        int gh = hi * 8 + xcd;
        b = sl[gh >> 4]; h = gh & 15; qtile = qt;
    }
    const int s0 = qtile * 64;
    const float lam = lams[b];

    const size_t bh = (size_t)b * NH + h;
    const ushort* Qh  = Qb + bh * NS * NDH;
    const ushort* Kh  = Kb + bh * NS * NDH;
    const ushort* Vh  = Vb + bh * NS * NDH;
    const ushort* Vth = Vt + bh * NDH * NS;

    if (!sparse) {
        const float nlam2 = -lam * LOG2E;   // base-2 bias

        // Q fragments (B-operand = Q^T) for this wave's 32 rows
        bf16x8 qf[2][2];
#pragma unroll
        for (int qh = 0; qh < 2; ++qh)
#pragma unroll
            for (int kk = 0; kk < 2; ++kk)
                qf[qh][kk] = *(const bf16x8*)
                    &Qh[(size_t)(s0 + wq*32 + qh*16 + l16) * NDH + kk*32 + quad*8];

        union { bf16x8 v; ushort s[8]; } ones;
#pragma unroll
        for (int i = 0; i < 8; ++i) ones.s[i] = 0x3F80;  // bf16 1.0

        f32x4 o_acc[2][4] = {};
        f32x4 l_acc[2] = {};

        for (int t = 0; t < 8; ++t) {
            if (t) __syncthreads();               // prior reads of KK done
            STAGE(2 * t);
            const int kt = 2 * t + wk;            // this wave's kt parity
            // mask words straight from L2-resident bm (prefetched here,
            // consumed after the QK cluster — latency hidden)
            u64 m0 = bm[(size_t)(s0 + wq*32 +  0 + l16) * 16 + kt];
            u64 m1 = bm[(size_t)(s0 + wq*32 + 16 + l16) * 16 + kt];
            __syncthreads();                      // stage visible
            bf16x8 kf[4][2], vf[4][2];
            LOADKV(kf, vf, kt);
            STEP(kf, vf, m0, m1);
        }
        __syncthreads();                          // KK/Ps dead -> POUT

        // ----- combine wk partials (o,l additive: no max normalization) ----
        float* POUT = (float*)SM;                 // 5120 floats = 20.5 KB
        if (wk == 1) {
#pragma unroll
            for (int qh = 0; qh < 2; ++qh) {
#pragma unroll
                for (int nt = 0; nt < 4; ++nt)
#pragma unroll
                    for (int rg = 0; rg < 4; ++rg)
                        POUT[(wq*40 + qh*16 + nt*4 + rg)*64 + lane] =
                            o_acc[qh][nt][rg];
#pragma unroll
                for (int rg = 0; rg < 4; ++rg)
                    POUT[(wq*40 + 32 + qh*4 + rg)*64 + lane] = l_acc[qh][rg];
            }
        }
        __syncthreads();
        if (wk == 0) {
#pragma unroll
            for (int qh = 0; qh < 2; ++qh) {
#pragma unroll
                for (int nt = 0; nt < 4; ++nt)
#pragma unroll
                    for (int rg = 0; rg < 4; ++rg)
                        o_acc[qh][nt][rg] +=
                            POUT[(wq*40 + qh*16 + nt*4 + rg)*64 + lane];
#pragma unroll
                for (int rg = 0; rg < 4; ++rg)
                    l_acc[qh][rg] += POUT[(wq*40 + 32 + qh*4 + rg)*64 + lane];
            }
            // epilogue (row=query quad*4+rg, col=dh nt*16+l16)
#pragma unroll
            for (int qh = 0; qh < 2; ++qh) {
                float inv[4];
#pragma unroll
                for (int rg = 0; rg < 4; ++rg) inv[rg] = 1.f / l_acc[qh][rg];
#pragma unroll
                for (int nt = 0; nt < 4; ++nt)
#pragma unroll
                    for (int rg = 0; rg < 4; ++rg) {
                        int m = wq*32 + qh*16 + quad*4 + rg;
                        OA[((size_t)b*NS + s0 + m)*ND + h*NDH + nt*16 + l16] =
                            f2bf(o_acc[qh][nt][rg] * inv[rg]);
                    }
            }
        }
    } else {
        // ---------------- sparse path (fp32 scalar, bf16 inputs) ----------
        const int r2  = lane & 15;
        const int cg  = lane >> 4;
        {
            const int row = w*16 + r2;            // 0..63

            float qreg[64];
            {
                const ushort* qp = Qh + (size_t)(s0 + row) * NDH;
#pragma unroll
                for (int c = 0; c < 8; ++c) {
                    union { bf16x8 v; ushort s[8]; } qv;
                    qv.v = *(const bf16x8*)(qp + c*8);
#pragma unroll
                    for (int j = 0; j < 8; ++j) qreg[c*8 + j] = bf2f(qv.s[j]);
                }
            }

            // scores: unconditional gather + select (no divergent branch)
            float sc[8];
#pragma unroll
            for (int jj = 0; jj < 8; ++jj) {
                int j  = cg*8 + jj;
                int mv = pimask[(size_t)(s0+row)*NKSP + j];
                int kv = pidx[(size_t)(s0+row)*NKSP + j];
                const ushort* krow = &Kh[(size_t)kv * NDH];
                float acc = 0.f;
#pragma unroll
                for (int c = 0; c < 8; ++c) {
                    union { bf16x8 v; ushort s[8]; } kk;
                    kk.v = *(const bf16x8*)(krow + c*8);
#pragma unroll
                    for (int jb = 0; jb < 8; ++jb)
                        acc = fmaf(qreg[c*8 + jb], bf2f(kk.s[jb]), acc);
                }
                sc[jj] = mv ? acc * SCALE : -INFINITY;
            }
            float mt = sc[0];
#pragma unroll
            for (int jj = 1; jj < 8; ++jj) mt = fmaxf(mt, sc[jj]);
            mt = fmaxf(mt, __shfl_xor(mt, 16));
            mt = fmaxf(mt, __shfl_xor(mt, 32));

            float psum = 0.f;
#pragma unroll
            for (int jj = 0; jj < 8; ++jj) {
                float p = __expf(sc[jj] - mt);
                psum += p;
                Ps[row * 72 + cg*8 + jj] = f2bf(p);
            }
            psum += __shfl_xor(psum, 16);
            psum += __shfl_xor(psum, 32);

            float o[16];
#pragma unroll
            for (int i = 0; i < 16; ++i) o[i] = 0.f;

            // PV: p=0 contributes 0 -> no branch; unroll for load pipelining
#pragma unroll 4
            for (int j = 0; j < 32; ++j) {
                float p = bf2f(Ps[row * 72 + j]);
                int kv = pidx[(size_t)(s0+row)*NKSP + j];
                const ushort* vrow = &Vh[(size_t)kv * NDH + cg*16];
#pragma unroll
                for (int c = 0; c < 2; ++c) {
                    union { bf16x8 v; ushort s[8]; } vv;
                    vv.v = *(const bf16x8*)(vrow + c*8);
#pragma unroll
                    for (int jb = 0; jb < 8; ++jb)
                        o[c*8 + jb] = fmaf(p, bf2f(vv.s[jb]), o[c*8 + jb]);
                }
            }

            float inv = 1.f / psum;
            ushort* op = OA + ((size_t)b*NS + s0 + row)*ND + h*NDH + cg*16;
#pragma unroll
            for (int i4 = 0; i4 < 4; ++i4) {
                ushort4 v;
                v.x = f2bf(o[i4*4+0]*inv); v.y = f2bf(o[i4*4+1]*inv);
                v.z = f2bf(o[i4*4+2]*inv); v.w = f2bf(o[i4*4+3]*inv);
                *(ushort4*)(op + i4*4) = v;
            }
        }
    }
}

// ---------------------------------------------------------------------------
extern "C" void kernel_launch(void* const* d_in, const int* in_sizes, int n_in,
                              void* d_out, int out_size, void* d_ws, size_t ws_size,
                              hipStream_t stream)
{
    const float* x      = (const float*)d_in[0];
    const int*   pmask  = (const int*)  d_in[1];
    const int*   pidx   = (const int*)  d_in[2];
    const int*   pimask = (const int*)  d_in[3];
    const float* u_prev = (const float*)d_in[4];
    const float* Wq     = (const float*)d_in[5];
    const float* bq     = (const float*)d_in[6];
    const float* Wk     = (const float*)d_in[7];
    const float* bk     = (const float*)d_in[8];
    const float* Wv     = (const float*)d_in[9];
    const float* bv     = (const float*)d_in[10];
    const float* Wo     = (const float*)d_in[11];
    const float* bo     = (const float*)d_in[12];
    float* out = (float*)d_out;

    const size_t QSZ = (size_t)NB * NH * NS * NDH;   // 4,194,304 elements
    const size_t WSZ = (size_t)ND * ND;              // 1,048,576 elements
    ushort* xb  = (ushort*)d_ws;        // bf16 x              (8 MB)
    ushort* Qw  = xb  + QSZ;            // bf16 Q (b,h,s,dh)   (8 MB)
    ushort* Kw  = Qw  + QSZ;            // bf16 K              (8 MB)
    ushort* Vw  = Kw  + QSZ;            // bf16 V              (8 MB)
    ushort* Vtw = Vw  + QSZ;            // bf16 V^T (b,h,dh,s) (8 MB)
    ushort* Awb = Vtw + QSZ;            // bf16 attn out       (8 MB)
    ushort* Wqb = Awb + QSZ;            // bf16 weights (2 MB each)
    ushort* Wkb = Wqb + WSZ;
    ushort* Wvb = Wkb + WSZ;
    ushort* Wob = Wvb + WSZ;
    u64*    bmw = (u64*)(Wob + WSZ);    // packed mask (128 KB)

    f2bf_multi<<<dim3(4096, 6), 256, 0, stream>>>(
        x, Wq, Wk, Wv, Wo, pmask, xb, Wqb, Wkb, Wvb, Wob, bmw);

    gemm_qkv<<<dim3(24, 32), 256, 0, stream>>>(
        xb, Wqb, Wkb, Wvb, bq, bk, bv, Qw, Kw, Vw, Vtw);

    attn_kernel<<<1024, 256, 0, stream>>>(
        Qw, Kw, Vw, Vtw, bmw, pidx, pimask, u_prev, Awb);

    gemm_out<<<dim3(ND/128, (NB*NS)/64), 256, 0, stream>>>(Awb, Wob, bo, out);
}